// Round 1
// 155.760 us; speedup vs baseline: 1.0343x; 1.0343x over previous
//
#include <hip/hip_runtime.h>
#include <math.h>

#define CB 8
#define CNX 512
#define CNR 512
#define CD 256
#define CH 256

__device__ __forceinline__ float fast_rcp(float x) {
#if __has_builtin(__builtin_amdgcn_rcpf)
  return __builtin_amdgcn_rcpf(x);
#else
  return 1.0f / x;
#endif
}
__device__ __forceinline__ float fast_exp2(float x) {
#if __has_builtin(__builtin_amdgcn_exp2f)
  return __builtin_amdgcn_exp2f(x);
#else
  return exp2f(x);
#endif
}

// Fused projections: z=0 -> exp(2*(X@W_X^T+b_X))^T, z=1 -> same for ref.
// ET[b][h][x] = exp2(K2L*(sum_k A[m][k]*W[h][k] + bias[h])), m=b*512+x
// 64(m) x 64(h) tile, K-tile 16, grid (64,4,2), block 256, 4x4 microtile.
// Register-staged prefetch: next K-tile's loads issue before the FMA loop.
__global__ __launch_bounds__(256) void proj_fused(
    const float* __restrict__ A0, const float* __restrict__ A1,
    const float* __restrict__ W0, const float* __restrict__ W1,
    const float* __restrict__ bias0, const float* __restrict__ bias1,
    float* __restrict__ E0, float* __restrict__ E1) {
  __shared__ float As[16][68];  // [k][m] padded
  __shared__ float Ws[16][68];  // [k][h] padded
  const int K = CD;
  int z = blockIdx.z;
  const float* A = z ? A1 : A0;
  const float* W = z ? W1 : W0;
  const float* bias = z ? bias1 : bias0;
  float* ET = z ? E1 : E0;
  int m0 = blockIdx.x * 64, n0 = blockIdx.y * 64;
  int tid = threadIdx.x;
  int tx = tid & 15, ty = tid >> 4;  // tx -> h, ty -> m(x)
  int lrow = tid >> 2, lc4 = tid & 3;
  float acc[4][4] = {};
  const float* pA = A + (size_t)(m0 + lrow) * K + lc4 * 4;
  const float* pW = W + (size_t)(n0 + lrow) * K + lc4 * 4;
  float4 av = *(const float4*)(pA);
  float4 wv = *(const float4*)(pW);
  for (int kt = 0; kt < K; kt += 16) {
    __syncthreads();
    As[lc4 * 4 + 0][lrow] = av.x;
    As[lc4 * 4 + 1][lrow] = av.y;
    As[lc4 * 4 + 2][lrow] = av.z;
    As[lc4 * 4 + 3][lrow] = av.w;
    Ws[lc4 * 4 + 0][lrow] = wv.x;
    Ws[lc4 * 4 + 1][lrow] = wv.y;
    Ws[lc4 * 4 + 2][lrow] = wv.z;
    Ws[lc4 * 4 + 3][lrow] = wv.w;
    __syncthreads();
    if (kt + 16 < K) {
      av = *(const float4*)(pA + kt + 16);
      wv = *(const float4*)(pW + kt + 16);
    }
#pragma unroll
    for (int k = 0; k < 16; k++) {
      float4 a4 = *(const float4*)&As[k][ty * 4];
      float4 w4 = *(const float4*)&Ws[k][tx * 4];
      float am[4] = {a4.x, a4.y, a4.z, a4.w};
      float wm[4] = {w4.x, w4.y, w4.z, w4.w};
#pragma unroll
      for (int i = 0; i < 4; i++)
#pragma unroll
        for (int j = 0; j < 4; j++)
          acc[i][j] = fmaf(am[i], wm[j], acc[i][j]);
    }
  }
  const float K2L = 2.8853900817779268f;  // 2*log2(e)
  float4 bv = *(const float4*)(bias + n0 + tx * 4);
  float bm[4] = {bv.x, bv.y, bv.z, bv.w};
  int b = m0 >> 9;
  int xbase = (m0 & 511) + ty * 4;
#pragma unroll
  for (int j = 0; j < 4; j++) {
    int h = n0 + tx * 4 + j;
    float4 o = {fast_exp2(K2L * (acc[0][j] + bm[j])),
                fast_exp2(K2L * (acc[1][j] + bm[j])),
                fast_exp2(K2L * (acc[2][j] + bm[j])),
                fast_exp2(K2L * (acc[3][j] + bm[j]))};
    *(float4*)(ET + ((size_t)b * CH + h) * CNX + xbase) = o;
  }
}

// scT[b][r][x] = -2 * sum_h v_w[h] / (exT[b][h][x]*erT[b][h][r] + 1)
// 4-way h-merge: sum v_i/a_i over 4 h via pairwise num/den combine.
// 64(x) x 64(r) tile, grid (8,8,8)=512 blocks, block 256, 4x4 microtile.
// LDS intensity: 2 B read per h-term (vs 4 in 2x2 version) -> VALU-bound.
#define HCH 32
__global__ __launch_bounds__(256) void scores_kernel(
    const float* __restrict__ exT, const float* __restrict__ erT,
    const float* __restrict__ v_w, float* __restrict__ scT) {
  __shared__ float xs[HCH][64];  // [h][x]
  __shared__ float rs[HCH][64];  // [h][r]
  __shared__ float vsh[CH];
  int b = blockIdx.z;
  int x0 = blockIdx.x * 64, r0 = blockIdx.y * 64;
  int tid = threadIdx.x;
  int tx = tid & 15, ty = tid >> 4;  // tx -> x(4), ty -> r(4)
  vsh[tid] = v_w[tid];
  // staging: 16 rows x 16 float4 cols, two row-passes per chunk
  int sr = ty, sc = tx * 4;
  const float* pX = exT + (size_t)b * CH * CNX + x0 + sc;
  const float* pR = erT + (size_t)b * CH * CNR + r0 + sc;
  float4 xa0 = *(const float4*)(pX + (size_t)sr * CNX);
  float4 xa1 = *(const float4*)(pX + (size_t)(sr + 16) * CNX);
  float4 ra0 = *(const float4*)(pR + (size_t)sr * CNR);
  float4 ra1 = *(const float4*)(pR + (size_t)(sr + 16) * CNR);
  float acc[4][4] = {};
  for (int hc = 0; hc < CH; hc += HCH) {
    __syncthreads();
    *(float4*)&xs[sr][sc] = xa0;
    *(float4*)&xs[sr + 16][sc] = xa1;
    *(float4*)&rs[sr][sc] = ra0;
    *(float4*)&rs[sr + 16][sc] = ra1;
    __syncthreads();
    if (hc + HCH < CH) {
      xa0 = *(const float4*)(pX + (size_t)(hc + HCH + sr) * CNX);
      xa1 = *(const float4*)(pX + (size_t)(hc + HCH + sr + 16) * CNX);
      ra0 = *(const float4*)(pR + (size_t)(hc + HCH + sr) * CNR);
      ra1 = *(const float4*)(pR + (size_t)(hc + HCH + sr + 16) * CNR);
    }
#pragma unroll 2
    for (int hq = 0; hq < HCH / 4; hq++) {
      int h0 = hq * 4;
      float4 vv = *(const float4*)&vsh[hc + h0];
      float4 xv0 = *(const float4*)&xs[h0 + 0][tx * 4];
      float4 xv1 = *(const float4*)&xs[h0 + 1][tx * 4];
      float4 xv2 = *(const float4*)&xs[h0 + 2][tx * 4];
      float4 xv3 = *(const float4*)&xs[h0 + 3][tx * 4];
      float4 rv0 = *(const float4*)&rs[h0 + 0][ty * 4];
      float4 rv1 = *(const float4*)&rs[h0 + 1][ty * 4];
      float4 rv2 = *(const float4*)&rs[h0 + 2][ty * 4];
      float4 rv3 = *(const float4*)&rs[h0 + 3][ty * 4];
      float xm0[4] = {xv0.x, xv0.y, xv0.z, xv0.w};
      float xm1[4] = {xv1.x, xv1.y, xv1.z, xv1.w};
      float xm2[4] = {xv2.x, xv2.y, xv2.z, xv2.w};
      float xm3[4] = {xv3.x, xv3.y, xv3.z, xv3.w};
      float rm0[4] = {rv0.x, rv0.y, rv0.z, rv0.w};
      float rm1[4] = {rv1.x, rv1.y, rv1.z, rv1.w};
      float rm2[4] = {rv2.x, rv2.y, rv2.z, rv2.w};
      float rm3[4] = {rv3.x, rv3.y, rv3.z, rv3.w};
#pragma unroll
      for (int i = 0; i < 4; i++)
#pragma unroll
        for (int j = 0; j < 4; j++) {
          float a = fmaf(rm0[i], xm0[j], 1.0f);
          float bb = fmaf(rm1[i], xm1[j], 1.0f);
          float c = fmaf(rm2[i], xm2[j], 1.0f);
          float d = fmaf(rm3[i], xm3[j], 1.0f);
          float q12 = a * bb, q34 = c * d;
          float p12 = fmaf(vv.y, a, vv.x * bb);
          float p34 = fmaf(vv.w, c, vv.z * d);
          float num = fmaf(p34, q12, p12 * q34);
          acc[i][j] = fmaf(num, fast_rcp(q12 * q34), acc[i][j]);
        }
    }
  }
  float* pO = scT + ((size_t)b * CNR + r0 + ty * 4) * CNX + x0 + tx * 4;
#pragma unroll
  for (int i = 0; i < 4; i++) {
    float4 o = {-2.0f * acc[i][0], -2.0f * acc[i][1],
                -2.0f * acc[i][2], -2.0f * acc[i][3]};
    *(float4*)(pO + (size_t)i * CNX) = o;
  }
}

// Fused softmax + weighted sum. Scores bounded (|s|<~26) so unnormalized
// exp(s) is fp32-safe; numerator and denominator in one K-loop.
// out[b][r][d] = sum_x e(b,r,x)*X[b][x][d] / sum_x e(b,r,x)
// 64(r) x 64(d) tile, K-tile 32, grid (8,4,8)=256 blocks, 4x4 microtile,
// register-staged prefetch (1 block/CU -> must hide HBM latency).
__global__ __launch_bounds__(256) void wsum_fused(
    const float* __restrict__ scT, const float* __restrict__ X,
    float* __restrict__ out) {
  __shared__ float As[32][68];  // [k][r] unnormalized attn
  __shared__ float Bs[32][68];  // [k][d]
  __shared__ float dn[64];
  const float L2E = 1.4426950408889634f;
  int b = blockIdx.z;
  int r0 = blockIdx.x * 64, d0 = blockIdx.y * 64;
  int tid = threadIdx.x;
  int tx = tid & 15, ty = tid >> 4;    // tx -> d(4), ty -> r(4)
  int ar = tid >> 2, ak = (tid & 3) * 4;   // scT: 64 r-rows, k = ak..ak+3, +16
  int br = tid >> 4, bc = (tid & 15) * 4;  // X: k-rows br, br+16; d cols bc
  const float* pS = scT + ((size_t)b * CNR + r0 + ar) * CNX + ak;
  const float* pB = X + (size_t)b * CNX * CD + d0 + bc;
  float acc[4][4] = {};
  float dsum = 0.0f;
  float4 s0 = *(const float4*)(pS);
  float4 s1 = *(const float4*)(pS + 16);
  float4 b0 = *(const float4*)(pB + (size_t)br * CD);
  float4 b1 = *(const float4*)(pB + (size_t)(br + 16) * CD);
  for (int kt = 0; kt < CNX; kt += 32) {
    float4 e0 = {fast_exp2(s0.x * L2E), fast_exp2(s0.y * L2E),
                 fast_exp2(s0.z * L2E), fast_exp2(s0.w * L2E)};
    float4 e1 = {fast_exp2(s1.x * L2E), fast_exp2(s1.y * L2E),
                 fast_exp2(s1.z * L2E), fast_exp2(s1.w * L2E)};
    dsum += ((e0.x + e0.y) + (e0.z + e0.w)) + ((e1.x + e1.y) + (e1.z + e1.w));
    __syncthreads();
    As[ak + 0][ar] = e0.x;
    As[ak + 1][ar] = e0.y;
    As[ak + 2][ar] = e0.z;
    As[ak + 3][ar] = e0.w;
    As[ak + 16][ar] = e1.x;
    As[ak + 17][ar] = e1.y;
    As[ak + 18][ar] = e1.z;
    As[ak + 19][ar] = e1.w;
    *(float4*)&Bs[br][bc] = b0;
    *(float4*)&Bs[br + 16][bc] = b1;
    __syncthreads();
    if (kt + 32 < CNX) {
      s0 = *(const float4*)(pS + kt + 32);
      s1 = *(const float4*)(pS + kt + 48);
      b0 = *(const float4*)(pB + (size_t)(kt + 32 + br) * CD);
      b1 = *(const float4*)(pB + (size_t)(kt + 32 + br + 16) * CD);
    }
#pragma unroll 8
    for (int k = 0; k < 32; k++) {
      float4 a4 = *(const float4*)&As[k][ty * 4];
      float4 b4 = *(const float4*)&Bs[k][tx * 4];
      float am[4] = {a4.x, a4.y, a4.z, a4.w};
      float bm[4] = {b4.x, b4.y, b4.z, b4.w};
#pragma unroll
      for (int i = 0; i < 4; i++)
#pragma unroll
        for (int j = 0; j < 4; j++)
          acc[i][j] = fmaf(am[i], bm[j], acc[i][j]);
    }
  }
  // row-sum of exp: 4 lanes (tid&3) share row ar
  dsum += __shfl_xor(dsum, 1, 64);
  dsum += __shfl_xor(dsum, 2, 64);
  if ((tid & 3) == 0) dn[ar] = dsum;
  __syncthreads();
  float invm[4] = {fast_rcp(dn[ty * 4 + 0]), fast_rcp(dn[ty * 4 + 1]),
                   fast_rcp(dn[ty * 4 + 2]), fast_rcp(dn[ty * 4 + 3])};
  float* pO = out + ((size_t)b * CNR + r0 + ty * 4) * CD + d0 + tx * 4;
#pragma unroll
  for (int i = 0; i < 4; i++) {
    float4 o = {acc[i][0] * invm[i], acc[i][1] * invm[i],
                acc[i][2] * invm[i], acc[i][3] * invm[i]};
    *(float4*)(pO + (size_t)i * CD) = o;
  }
}

extern "C" void kernel_launch(void* const* d_in, const int* in_sizes, int n_in,
                              void* d_out, int out_size, void* d_ws, size_t ws_size,
                              hipStream_t stream) {
  const float* X     = (const float*)d_in[0];
  const float* ref   = (const float*)d_in[1];
  const float* W_X   = (const float*)d_in[2];
  const float* b_X   = (const float*)d_in[3];
  const float* W_ref = (const float*)d_in[4];
  const float* b_ref = (const float*)d_in[5];
  const float* v_w   = (const float*)d_in[6];
  float* out = (float*)d_out;
  float* ws  = (float*)d_ws;

  float* exT = ws;                       // [B][H][NX] = 1,048,576 floats
  float* erT = ws + 1048576;             // [B][H][NR] = 1,048,576 floats
  float* scT = ws + 2097152;             // [B][NR][NX] = 2,097,152 floats

  proj_fused<<<dim3(64, 4, 2), 256, 0, stream>>>(X, ref, W_X, W_ref, b_X, b_ref, exT, erT);
  scores_kernel<<<dim3(8, 8, 8), 256, 0, stream>>>(exT, erT, v_w, scT);
  wsum_fused<<<dim3(8, 4, 8), 256, 0, stream>>>(scT, X, out);
}

// Round 2
// 152.516 us; speedup vs baseline: 1.0563x; 1.0213x over previous
//
#include <hip/hip_runtime.h>
#include <math.h>

#define CB 8
#define CNX 512
#define CNR 512
#define CD 256
#define CH 256

__device__ __forceinline__ float fast_rcp(float x) {
#if __has_builtin(__builtin_amdgcn_rcpf)
  return __builtin_amdgcn_rcpf(x);
#else
  return 1.0f / x;
#endif
}
__device__ __forceinline__ float fast_exp2(float x) {
#if __has_builtin(__builtin_amdgcn_exp2f)
  return __builtin_amdgcn_exp2f(x);
#else
  return exp2f(x);
#endif
}

// Fused projections: z=0 -> exp(2*(X@W_X^T+b_X))^T, z=1 -> same for ref.
// ET[b][h][x] = exp2(K2L*(sum_k A[m][k]*W[h][k] + bias[h])), m=b*512+x
// 64(m) x 64(h) tile, K-tile 16, grid (64,4,2), block 256, 4x4 microtile.
// Register-staged prefetch: next K-tile's loads issue before the FMA loop.
__global__ __launch_bounds__(256) void proj_fused(
    const float* __restrict__ A0, const float* __restrict__ A1,
    const float* __restrict__ W0, const float* __restrict__ W1,
    const float* __restrict__ bias0, const float* __restrict__ bias1,
    float* __restrict__ E0, float* __restrict__ E1) {
  __shared__ float As[16][68];  // [k][m] padded
  __shared__ float Ws[16][68];  // [k][h] padded
  const int K = CD;
  int z = blockIdx.z;
  const float* A = z ? A1 : A0;
  const float* W = z ? W1 : W0;
  const float* bias = z ? bias1 : bias0;
  float* ET = z ? E1 : E0;
  int m0 = blockIdx.x * 64, n0 = blockIdx.y * 64;
  int tid = threadIdx.x;
  int tx = tid & 15, ty = tid >> 4;  // tx -> h, ty -> m(x)
  int lrow = tid >> 2, lc4 = tid & 3;
  float acc[4][4] = {};
  const float* pA = A + (size_t)(m0 + lrow) * K + lc4 * 4;
  const float* pW = W + (size_t)(n0 + lrow) * K + lc4 * 4;
  float4 av = *(const float4*)(pA);
  float4 wv = *(const float4*)(pW);
  for (int kt = 0; kt < K; kt += 16) {
    __syncthreads();
    As[lc4 * 4 + 0][lrow] = av.x;
    As[lc4 * 4 + 1][lrow] = av.y;
    As[lc4 * 4 + 2][lrow] = av.z;
    As[lc4 * 4 + 3][lrow] = av.w;
    Ws[lc4 * 4 + 0][lrow] = wv.x;
    Ws[lc4 * 4 + 1][lrow] = wv.y;
    Ws[lc4 * 4 + 2][lrow] = wv.z;
    Ws[lc4 * 4 + 3][lrow] = wv.w;
    __syncthreads();
    if (kt + 16 < K) {
      av = *(const float4*)(pA + kt + 16);
      wv = *(const float4*)(pW + kt + 16);
    }
#pragma unroll
    for (int k = 0; k < 16; k++) {
      float4 a4 = *(const float4*)&As[k][ty * 4];
      float4 w4 = *(const float4*)&Ws[k][tx * 4];
      float am[4] = {a4.x, a4.y, a4.z, a4.w};
      float wm[4] = {w4.x, w4.y, w4.z, w4.w};
#pragma unroll
      for (int i = 0; i < 4; i++)
#pragma unroll
        for (int j = 0; j < 4; j++)
          acc[i][j] = fmaf(am[i], wm[j], acc[i][j]);
    }
  }
  const float K2L = 2.8853900817779268f;  // 2*log2(e)
  float4 bv = *(const float4*)(bias + n0 + tx * 4);
  float bm[4] = {bv.x, bv.y, bv.z, bv.w};
  int b = m0 >> 9;
  int xbase = (m0 & 511) + ty * 4;
#pragma unroll
  for (int j = 0; j < 4; j++) {
    int h = n0 + tx * 4 + j;
    float4 o = {fast_exp2(K2L * (acc[0][j] + bm[j])),
                fast_exp2(K2L * (acc[1][j] + bm[j])),
                fast_exp2(K2L * (acc[2][j] + bm[j])),
                fast_exp2(K2L * (acc[3][j] + bm[j]))};
    *(float4*)(ET + ((size_t)b * CH + h) * CNX + xbase) = o;
  }
}

// scT[b][r][x] = -2 * sum_h v_w[h] / (exT[b][h][x]*erT[b][h][r] + 1)
// 64(x) x 64(r) tile, grid (8,8,8)=512 blocks, block 512 (two 256-thread
// groups h-splitting the reduction -> 8 waves/block = 4 waves/SIMD),
// 4x4 microtile, LDS partial-merge epilogue.
__global__ __launch_bounds__(512) void scores_kernel(
    const float* __restrict__ exT, const float* __restrict__ erT,
    const float* __restrict__ v_w, float* __restrict__ scT) {
  // layout: xs0[32*64] rs0[32*64] xs1[32*64] rs1[32*64] vsh[256]
  __shared__ float smem[4 * 2048 + 256];
  int b = blockIdx.z;
  int x0 = blockIdx.x * 64, r0 = blockIdx.y * 64;
  int tid = threadIdx.x;
  int g = tid >> 8;      // reduction group
  int t = tid & 255;
  float* xs = smem + g * 4096;   // [32][64]
  float* rs = xs + 2048;         // [32][64]
  float* vsh = smem + 8192;
  if (tid < 256) vsh[tid] = v_w[tid];
  int tx = t & 15, ty = t >> 4;  // tx -> x(4), ty -> r(4)
  int sr = t >> 4, sc = (t & 15) * 4;  // staging: 16 rows x 16 float4
  const float* pX = exT + (size_t)b * CH * CNX + x0 + sc;
  const float* pR = erT + (size_t)b * CH * CNR + r0 + sc;
  int hb = g * 32;
  float4 xa0 = *(const float4*)(pX + (size_t)(hb + sr) * CNX);
  float4 xa1 = *(const float4*)(pX + (size_t)(hb + sr + 16) * CNX);
  float4 ra0 = *(const float4*)(pR + (size_t)(hb + sr) * CNR);
  float4 ra1 = *(const float4*)(pR + (size_t)(hb + sr + 16) * CNR);
  float acc[4][4] = {};
  for (int hc = hb; hc < CH; hc += 64) {
    __syncthreads();
    *(float4*)&xs[sr * 64 + sc] = xa0;
    *(float4*)&xs[(sr + 16) * 64 + sc] = xa1;
    *(float4*)&rs[sr * 64 + sc] = ra0;
    *(float4*)&rs[(sr + 16) * 64 + sc] = ra1;
    __syncthreads();
    if (hc + 64 < CH) {
      xa0 = *(const float4*)(pX + (size_t)(hc + 64 + sr) * CNX);
      xa1 = *(const float4*)(pX + (size_t)(hc + 64 + sr + 16) * CNX);
      ra0 = *(const float4*)(pR + (size_t)(hc + 64 + sr) * CNR);
      ra1 = *(const float4*)(pR + (size_t)(hc + 64 + sr + 16) * CNR);
    }
#pragma unroll 2
    for (int hq = 0; hq < 8; hq++) {
      int h0 = hq * 4;
      float4 vv = *(const float4*)&vsh[hc + h0];
      float4 xv0 = *(const float4*)&xs[(h0 + 0) * 64 + tx * 4];
      float4 xv1 = *(const float4*)&xs[(h0 + 1) * 64 + tx * 4];
      float4 xv2 = *(const float4*)&xs[(h0 + 2) * 64 + tx * 4];
      float4 xv3 = *(const float4*)&xs[(h0 + 3) * 64 + tx * 4];
      float4 rv0 = *(const float4*)&rs[(h0 + 0) * 64 + ty * 4];
      float4 rv1 = *(const float4*)&rs[(h0 + 1) * 64 + ty * 4];
      float4 rv2 = *(const float4*)&rs[(h0 + 2) * 64 + ty * 4];
      float4 rv3 = *(const float4*)&rs[(h0 + 3) * 64 + ty * 4];
      float xm0[4] = {xv0.x, xv0.y, xv0.z, xv0.w};
      float xm1[4] = {xv1.x, xv1.y, xv1.z, xv1.w};
      float xm2[4] = {xv2.x, xv2.y, xv2.z, xv2.w};
      float xm3[4] = {xv3.x, xv3.y, xv3.z, xv3.w};
      float rm0[4] = {rv0.x, rv0.y, rv0.z, rv0.w};
      float rm1[4] = {rv1.x, rv1.y, rv1.z, rv1.w};
      float rm2[4] = {rv2.x, rv2.y, rv2.z, rv2.w};
      float rm3[4] = {rv3.x, rv3.y, rv3.z, rv3.w};
#pragma unroll
      for (int i = 0; i < 4; i++)
#pragma unroll
        for (int j = 0; j < 4; j++) {
          float a = fmaf(rm0[i], xm0[j], 1.0f);
          float bb = fmaf(rm1[i], xm1[j], 1.0f);
          float c = fmaf(rm2[i], xm2[j], 1.0f);
          float d = fmaf(rm3[i], xm3[j], 1.0f);
          float q12 = a * bb, q34 = c * d;
          float p12 = fmaf(vv.y, a, vv.x * bb);
          float p34 = fmaf(vv.w, c, vv.z * d);
          float num = fmaf(p34, q12, p12 * q34);
          acc[i][j] = fmaf(num, fast_rcp(q12 * q34), acc[i][j]);
        }
    }
  }
  // merge the two h-partials (reuse smem[0..4096) after barrier)
  __syncthreads();
  float* mg = smem;
  if (g == 1) {
#pragma unroll
    for (int i = 0; i < 4; i++)
#pragma unroll
      for (int j = 0; j < 4; j++)
        mg[t + 256 * (i * 4 + j)] = acc[i][j];
  }
  __syncthreads();
  if (g == 0) {
    float* pO = scT + ((size_t)b * CNR + r0 + ty * 4) * CNX + x0 + tx * 4;
#pragma unroll
    for (int i = 0; i < 4; i++) {
      float4 o = {-2.0f * (acc[i][0] + mg[t + 256 * (i * 4 + 0)]),
                  -2.0f * (acc[i][1] + mg[t + 256 * (i * 4 + 1)]),
                  -2.0f * (acc[i][2] + mg[t + 256 * (i * 4 + 2)]),
                  -2.0f * (acc[i][3] + mg[t + 256 * (i * 4 + 3)])};
      *(float4*)(pO + (size_t)i * CNX) = o;
    }
  }
}

// Fused softmax + weighted sum. Scores bounded so unnormalized exp(s) is
// fp32-safe; numerator and denominator in one K-loop.
// out[b][r][d] = sum_x e(b,r,x)*X[b][x][d] / sum_x e(b,r,x)
// 64(r) x 64(d) tile, grid (8,4,8)=256 blocks, block 512 (two 256-thread
// groups x-splitting the K loop -> 8 waves/CU), 4x4 microtile, prefetch.
__global__ __launch_bounds__(512) void wsum_fused(
    const float* __restrict__ scT, const float* __restrict__ X,
    float* __restrict__ out) {
  // layout: As0[32*68] Bs0[32*68] As1[32*68] Bs1[32*68] dn[128]
  __shared__ float smem[4 * 2176 + 128];
  const float L2E = 1.4426950408889634f;
  int b = blockIdx.z;
  int r0 = blockIdx.x * 64, d0 = blockIdx.y * 64;
  int tid = threadIdx.x;
  int g = tid >> 8;
  int t = tid & 255;
  float* As = smem + g * 4352;   // [32][68] [k][r]
  float* Bs = As + 2176;         // [32][68] [k][d]
  float* dnn = smem + 8704;      // [2][64]
  int tx = t & 15, ty = t >> 4;        // tx -> d(4), ty -> r(4)
  int ar = t >> 2, ak = (t & 3) * 4;   // scT: 64 r-rows, k = ak..ak+3, +16
  int br = t >> 4, bc = (t & 15) * 4;  // X: k-rows br, br+16; d cols bc
  int kb = g * 32;
  const float* pS = scT + ((size_t)b * CNR + r0 + ar) * CNX + ak;
  const float* pB = X + (size_t)b * CNX * CD + d0 + bc;
  float acc[4][4] = {};
  float dsum = 0.0f;
  float4 s0 = *(const float4*)(pS + kb);
  float4 s1 = *(const float4*)(pS + kb + 16);
  float4 b0 = *(const float4*)(pB + (size_t)(kb + br) * CD);
  float4 b1 = *(const float4*)(pB + (size_t)(kb + br + 16) * CD);
  for (int kt = kb; kt < CNX; kt += 64) {
    float4 e0 = {fast_exp2(s0.x * L2E), fast_exp2(s0.y * L2E),
                 fast_exp2(s0.z * L2E), fast_exp2(s0.w * L2E)};
    float4 e1 = {fast_exp2(s1.x * L2E), fast_exp2(s1.y * L2E),
                 fast_exp2(s1.z * L2E), fast_exp2(s1.w * L2E)};
    dsum += ((e0.x + e0.y) + (e0.z + e0.w)) + ((e1.x + e1.y) + (e1.z + e1.w));
    __syncthreads();
    As[(ak + 0) * 68 + ar] = e0.x;
    As[(ak + 1) * 68 + ar] = e0.y;
    As[(ak + 2) * 68 + ar] = e0.z;
    As[(ak + 3) * 68 + ar] = e0.w;
    As[(ak + 16) * 68 + ar] = e1.x;
    As[(ak + 17) * 68 + ar] = e1.y;
    As[(ak + 18) * 68 + ar] = e1.z;
    As[(ak + 19) * 68 + ar] = e1.w;
    *(float4*)&Bs[br * 68 + bc] = b0;
    *(float4*)&Bs[(br + 16) * 68 + bc] = b1;
    __syncthreads();
    if (kt + 64 < CNX) {
      s0 = *(const float4*)(pS + kt + 64);
      s1 = *(const float4*)(pS + kt + 80);
      b0 = *(const float4*)(pB + (size_t)(kt + 64 + br) * CD);
      b1 = *(const float4*)(pB + (size_t)(kt + 64 + br + 16) * CD);
    }
#pragma unroll 8
    for (int k = 0; k < 32; k++) {
      float4 a4 = *(const float4*)&As[k * 68 + ty * 4];
      float4 b4 = *(const float4*)&Bs[k * 68 + tx * 4];
      float am[4] = {a4.x, a4.y, a4.z, a4.w};
      float bm[4] = {b4.x, b4.y, b4.z, b4.w};
#pragma unroll
      for (int i = 0; i < 4; i++)
#pragma unroll
        for (int j = 0; j < 4; j++)
          acc[i][j] = fmaf(am[i], bm[j], acc[i][j]);
    }
  }
  // denominator partial: 4 lanes (t&3) share row ar
  dsum += __shfl_xor(dsum, 1, 64);
  dsum += __shfl_xor(dsum, 2, 64);
  if ((t & 3) == 0) dnn[g * 64 + ar] = dsum;
  __syncthreads();
  // merge the two x-partials (reuse smem[0..4096) after barrier; dn is safe)
  float* mg = smem;
  if (g == 1) {
#pragma unroll
    for (int i = 0; i < 4; i++)
#pragma unroll
      for (int j = 0; j < 4; j++)
        mg[t + 256 * (i * 4 + j)] = acc[i][j];
  }
  __syncthreads();
  if (g == 0) {
    float invm[4];
#pragma unroll
    for (int i = 0; i < 4; i++)
      invm[i] = fast_rcp(dnn[ty * 4 + i] + dnn[64 + ty * 4 + i]);
    float* pO = out + ((size_t)b * CNR + r0 + ty * 4) * CD + d0 + tx * 4;
#pragma unroll
    for (int i = 0; i < 4; i++) {
      float4 o = {
          (acc[i][0] + mg[t + 256 * (i * 4 + 0)]) * invm[i],
          (acc[i][1] + mg[t + 256 * (i * 4 + 1)]) * invm[i],
          (acc[i][2] + mg[t + 256 * (i * 4 + 2)]) * invm[i],
          (acc[i][3] + mg[t + 256 * (i * 4 + 3)]) * invm[i]};
      *(float4*)(pO + (size_t)i * CD) = o;
    }
  }
}

extern "C" void kernel_launch(void* const* d_in, const int* in_sizes, int n_in,
                              void* d_out, int out_size, void* d_ws, size_t ws_size,
                              hipStream_t stream) {
  const float* X     = (const float*)d_in[0];
  const float* ref   = (const float*)d_in[1];
  const float* W_X   = (const float*)d_in[2];
  const float* b_X   = (const float*)d_in[3];
  const float* W_ref = (const float*)d_in[4];
  const float* b_ref = (const float*)d_in[5];
  const float* v_w   = (const float*)d_in[6];
  float* out = (float*)d_out;
  float* ws  = (float*)d_ws;

  float* exT = ws;                       // [B][H][NX] = 1,048,576 floats
  float* erT = ws + 1048576;             // [B][H][NR] = 1,048,576 floats
  float* scT = ws + 2097152;             // [B][NR][NX] = 2,097,152 floats

  proj_fused<<<dim3(64, 4, 2), 256, 0, stream>>>(X, ref, W_X, W_ref, b_X, b_ref, exT, erT);
  scores_kernel<<<dim3(8, 8, 8), 512, 0, stream>>>(exT, erT, v_w, scT);
  wsum_fused<<<dim3(8, 4, 8), 512, 0, stream>>>(scT, X, out);
}